// Round 9
// baseline (281.379 us; speedup 1.0000x reference)
//
#include <hip/hip_runtime.h>

// ---------- types / helpers ----------
typedef __attribute__((ext_vector_type(8))) short bfrag;   // 8 bf16 in 4 VGPRs
typedef __attribute__((ext_vector_type(4))) float f32x4;

__device__ __forceinline__ f32x4 mfma16(bfrag a, bfrag b, f32x4 c) {
    return __builtin_amdgcn_mfma_f32_16x16x32_bf16(a, b, c, 0, 0, 0);
}
// fp32 -> bf16 round-to-nearest-even
__device__ __forceinline__ unsigned short f2bf(float f) {
    unsigned int u = __float_as_uint(f);
    u = u + 0x7fffu + ((u >> 16) & 1u);
    return (unsigned short)(u >> 16);
}
// async global->LDS DMA, 16B/lane
__device__ __forceinline__ void glds16(const unsigned short* g, unsigned short* l) {
    __builtin_amdgcn_global_load_lds(
        (const __attribute__((address_space(1))) void*)g,
        (__attribute__((address_space(3))) void*)l, 16, 0, 0);
}

#define DIM 256
#define BT  16384          // B*T = 4*4096
#define TSEQ 4096
#define FB   1048576       // ushorts per batch in KF/VF

// FRAG-MAJOR layout for ALL MFMA operands:
//   F[tile16][ks][slot = q*16+r][8]   (frag = 512 ushorts = 1KB)
//   slot(q,r) holds M[row = tile*16 + r][k = ks*32 + q*8 .. +8]
// One wave-load / one glds16 = one contiguous 1KB fragment.

// ---------- kernel 1: weights -> frag-major bf16, RMSNorm1 -> frag-major xnF ----------
__global__ __launch_bounds__(256) void k_prep(
    const float* __restrict__ x, const float* __restrict__ anw,
    const float* __restrict__ wq, const float* __restrict__ wk,
    const float* __restrict__ wv, const float* __restrict__ wo,
    const float* __restrict__ w1, const float* __restrict__ w2,
    unsigned short* __restrict__ wqF, unsigned short* __restrict__ wkF,
    unsigned short* __restrict__ wvF, unsigned short* __restrict__ woF,
    unsigned short* __restrict__ w1F, unsigned short* __restrict__ w2F,
    unsigned short* __restrict__ xnF)
{
    int bid = blockIdx.x;
    int wave = threadIdx.x >> 6, lane = threadIdx.x & 63;
    int q = lane >> 4, r = lane & 15;
    if (bid < 384) {
        int fid = bid * 4 + wave;                    // 0..1535
        const float* src; unsigned short* dst; int ntile, ks, K, fbase;
        if (fid < 512) {
            int w = fid >> 7, fl = fid & 127;
            ntile = fl >> 3; ks = fl & 7; K = 256;
            src = (w == 0) ? wq : (w == 1) ? wk : (w == 2) ? wv : wo;
            dst = (w == 0) ? wqF : (w == 1) ? wkF : (w == 2) ? wvF : woF;
            fbase = (ntile * 8 + ks) * 512;
        } else if (fid < 1024) {
            int fl = fid - 512;
            ntile = fl >> 3; ks = fl & 7; K = 256;
            src = w1; dst = w1F;
            fbase = (ntile * 8 + ks) * 512;
        } else {
            int fl = fid - 1024;
            ntile = fl >> 5; ks = fl & 31; K = 1024;
            src = w2; dst = w2F;
            fbase = (ntile * 32 + ks) * 512;
        }
        const float* s = src + (ntile * 16 + r) * K + ks * 32 + q * 8;
        float4 v0 = *(const float4*)(s);
        float4 v1 = *(const float4*)(s + 4);
        unsigned short o[8] = { f2bf(v0.x), f2bf(v0.y), f2bf(v0.z), f2bf(v0.w),
                                f2bf(v1.x), f2bf(v1.y), f2bf(v1.z), f2bf(v1.w) };
        *(ushort4*)(dst + fbase + lane * 8)     = make_ushort4(o[0], o[1], o[2], o[3]);
        *(ushort4*)(dst + fbase + lane * 8 + 4) = make_ushort4(o[4], o[5], o[6], o[7]);
    } else {
        int row  = (bid - 384) * 4 + wave;
        float4 v = *(const float4*)(x + row * DIM + lane * 4);
        float ss = v.x*v.x + v.y*v.y + v.z*v.z + v.w*v.w;
        #pragma unroll
        for (int off = 1; off < 64; off <<= 1) ss += __shfl_xor(ss, off);
        float inv = rsqrtf(ss * (1.0f / DIM) + 1e-6f);
        float4 w = *(const float4*)(anw + lane * 4);
        ushort4 o = make_ushort4(f2bf(v.x*inv*w.x), f2bf(v.y*inv*w.y),
                                 f2bf(v.z*inv*w.z), f2bf(v.w*inv*w.w));
        int c = lane * 4;
        int ks = c >> 5, qp = (c >> 3) & 3, e0 = c & 7;
        *(ushort4*)(xnF + (((row >> 4) * 8 + ks) * 512) + ((qp * 16 + (row & 15)) * 8) + e0) = o;
    }
}

// ============ glds-staged GEMM pattern ============
// Per ks-step: 20 frags (A:4 shared, B:16) into 2x20KB LDS double buffer.
// Wave w DMAs frags [w*5, w*5+5). vmcnt(5) = own previous stage done;
// raw s_barrier (manual waitcnt, no full drain) for collective completion;
// second barrier before buffer overwrite.

// ---------- kernel 2: QKV GEMM (M=16384, N=768 virtual, K=256) ----------
__global__ __launch_bounds__(256) void k_qkv(
    const unsigned short* __restrict__ xnF,
    const unsigned short* __restrict__ wqF, const unsigned short* __restrict__ wkF,
    const unsigned short* __restrict__ wvF,
    const float* __restrict__ bq, const float* __restrict__ bk, const float* __restrict__ bv,
    unsigned short* __restrict__ Q, unsigned short* __restrict__ KF,
    unsigned short* __restrict__ VF)
{
    __shared__ __align__(16) unsigned short sb[2][20 * 512];
    int bid = blockIdx.x;
    int wave = threadIdx.x >> 6, lane = threadIdx.x & 63;
    int m0 = (bid / 3) * 64;
    int grp = bid % 3;                         // 0=Q 1=K 2=V (block-uniform)
    int nc  = wave * 64;                       // col base within the selected matrix
    const unsigned short* WF = (grp == 0) ? wqF : (grp == 1) ? wkF : wvF;
    const float* bias        = (grp == 0) ? bq  : (grp == 1) ? bk  : bv;
    int q = lane >> 4, r = lane & 15;
    int lane8 = lane * 8;
    int mt = m0 >> 4;

    // stage frag f at ks: f<4 -> A(mt+f), else B ntile (f-4)
    #define QKV_STAGE(ks, buf)                                                   \
        { int _k = (ks);                                                         \
          _Pragma("unroll")                                                      \
          for (int t = 0; t < 5; ++t) {                                          \
              int f = wave * 5 + t;                                              \
              const unsigned short* g = (f < 4)                                  \
                  ? xnF + ((mt + f) * 8 + _k) * 512                              \
                  : WF  + ((f - 4) * 8 + _k) * 512;                              \
              glds16(g + lane8, &sb[buf][f * 512]);                              \
          } }

    f32x4 acc[4][4] = {};
    QKV_STAGE(0, 0)
    for (int ks = 0; ks < 8; ++ks) {
        int cur = ks & 1;
        if (ks + 1 < 8) { QKV_STAGE(ks + 1, cur ^ 1) }
        if (ks + 1 < 8) asm volatile("s_waitcnt vmcnt(5)" ::: "memory");
        else            asm volatile("s_waitcnt vmcnt(0)" ::: "memory");
        asm volatile("s_barrier" ::: "memory");
        bfrag a[4], b[4];
        #pragma unroll
        for (int i = 0; i < 4; ++i) a[i] = *(const bfrag*)(&sb[cur][i * 512] + lane8);
        #pragma unroll
        for (int j = 0; j < 4; ++j) b[j] = *(const bfrag*)(&sb[cur][(4 + wave * 4 + j) * 512] + lane8);
        #pragma unroll
        for (int i = 0; i < 4; ++i)
            #pragma unroll
            for (int j = 0; j < 4; ++j) acc[i][j] = mfma16(a[i], b[j], acc[i][j]);
        asm volatile("s_barrier" ::: "memory");
    }
    #undef QKV_STAGE

    if (grp == 0) {
        #pragma unroll
        for (int j = 0; j < 4; ++j) {
            int col = nc + j * 16 + r;
            float bz = bias[col];
            #pragma unroll
            for (int i = 0; i < 4; ++i)
                #pragma unroll
                for (int g = 0; g < 4; ++g) {
                    int row = m0 + i * 16 + q * 4 + g;
                    Q[row * DIM + col] = f2bf(acc[i][j][g] + bz);
                }
        }
    } else if (grp == 1) {
        #pragma unroll
        for (int j = 0; j < 4; ++j) {
            int col = nc + j * 16 + r;
            int ks = col >> 5, qc = (col >> 3) & 3, e = col & 7;
            float bz = bias[col];
            #pragma unroll
            for (int i = 0; i < 4; ++i)
                #pragma unroll
                for (int g = 0; g < 4; ++g) {
                    int row = m0 + i * 16 + q * 4 + g;
                    int bb = row >> 12;
                    int r5 = row & 31, tile = (row & 4095) >> 5;
                    int h = (r5 >> 2) & 1;
                    int rc = ((r5 >> 3) << 2) | (r5 & 3);
                    KF[bb * FB + (tile * 16 + ks * 2 + h) * 512 + (qc * 16 + rc) * 8 + e]
                        = f2bf(acc[i][j][g] + bz);
                }
        }
    } else {
        #pragma unroll
        for (int j = 0; j < 4; ++j) {
            int vd = nc + j * 16 + r;
            int jc = vd >> 4, rc = vd & 15;
            float bz = bias[vd];
            #pragma unroll
            for (int i = 0; i < 4; ++i) {
                int t0 = m0 + i * 16 + q * 4;
                int bb = t0 >> 12, tl = t0 & (TSEQ - 1);
                int tile = tl >> 5, qc = (tl >> 3) & 3, e0 = tl & 7;
                ushort4 o = make_ushort4(f2bf(acc[i][j][0] + bz), f2bf(acc[i][j][1] + bz),
                                         f2bf(acc[i][j][2] + bz), f2bf(acc[i][j][3] + bz));
                *(ushort4*)(VF + bb * FB + (tile * 16 + jc) * 512 + (qc * 16 + rc) * 8 + e0) = o;
            }
        }
    }
}

// ---------- kernel 3: causal flash attention (unchanged from R7) ----------
__global__ __launch_bounds__(128, 1) void k_attn(
    const unsigned short* __restrict__ Q, const unsigned short* __restrict__ KF,
    const unsigned short* __restrict__ VF, unsigned short* __restrict__ AOF)
{
    __shared__ __align__(16) unsigned char arena[65536];
    int bid = blockIdx.x;
    int xcd = bid & 7;
    int batch = xcd >> 1;
    int qt = 255 - (((bid >> 3) << 1) | (xcd & 1));
    int wave = threadIdx.x >> 6;
    int lane = threadIdx.x & 63;
    int q = lane >> 4, r = lane & 15;
    int q0 = qt * 16;
    const unsigned short* Qb  = Q  + (size_t)batch * TSEQ * DIM;
    const unsigned short* KFb = KF + (size_t)batch * FB;
    const unsigned short* VFb = VF + (size_t)batch * FB;
    int lane8 = lane * 8;

    unsigned short* Kl = (unsigned short*)(arena + wave * 32768);
    unsigned short* Vl = Kl + 8192;

    bfrag qf[8];
    #pragma unroll
    for (int ks = 0; ks < 8; ++ks)
        qf[ks] = *(const bfrag*)(Qb + (q0 + r) * DIM + ks * 32 + q * 8);

    f32x4 o[16] = {};
    float lsum = 0.f;

    int ktiles = (q0 + 16 + 31) >> 5;
    int half = ktiles >> 1, rem = ktiles & 1;
    int cnt   = half + (wave == 0 ? rem : 0);
    int start = (wave == 0) ? 0 : half + rem;

    if (cnt > 0) {
        const unsigned short* kg = KFb + (size_t)start * 8192;
        #pragma unroll
        for (int f = 0; f < 16; ++f) glds16(kg + f * 512 + lane8, Kl + f * 512);
        const unsigned short* vg = VFb + (size_t)start * 8192;
        #pragma unroll
        for (int j = 0; j < 16; ++j) glds16(vg + j * 512 + lane8, Vl + j * 512);
    }

    for (int i = 0; i < cnt; ++i) {
        int kt = start + i;
        bool more = (i + 1 < cnt);
        asm volatile("s_waitcnt vmcnt(16)" ::: "memory");
        bfrag kb0[8], kb1[8];
        #pragma unroll
        for (int ks = 0; ks < 8; ++ks) {
            kb0[ks] = *(const bfrag*)(Kl + (ks * 2    ) * 512 + lane8);
            kb1[ks] = *(const bfrag*)(Kl + (ks * 2 + 1) * 512 + lane8);
        }
        f32x4 s0 = {}, s1 = {};
        #pragma unroll
        for (int ks = 0; ks < 8; ++ks) {
            s0 = mfma16(kb0[ks], qf[ks], s0);
            s1 = mfma16(kb1[ks], qf[ks], s1);
        }
        if (more) {
            asm volatile("s_waitcnt lgkmcnt(0)" ::: "memory");
            const unsigned short* kg = KFb + (size_t)(kt + 1) * 8192;
            #pragma unroll
            for (int f = 0; f < 16; ++f) glds16(kg + f * 512 + lane8, Kl + f * 512);
        }
        int kk0 = kt * 32;
        bool lastt = (kt == ktiles - 1);
        int qglob = q0 + r;
        bfrag pf;
        #pragma unroll
        for (int g = 0; g < 4; ++g) {
            int key0 = kk0 + q * 8 + g;
            float p0 = (lastt && key0     > qglob) ? 0.f : __expf(s0[g] * 0.0625f);
            float p1 = (lastt && key0 + 4 > qglob) ? 0.f : __expf(s1[g] * 0.0625f);
            lsum += p0 + p1;
            pf[g]     = (short)f2bf(p0);
            pf[g + 4] = (short)f2bf(p1);
        }
        if (more) asm volatile("s_waitcnt vmcnt(16)" ::: "memory");
        else      asm volatile("s_waitcnt vmcnt(0)"  ::: "memory");
        #pragma unroll
        for (int j = 0; j < 16; ++j) {
            bfrag vb = *(const bfrag*)(Vl + j * 512 + lane8);
            o[j] = mfma16(pf, vb, o[j]);
        }
        if (more) {
            asm volatile("s_waitcnt lgkmcnt(0)" ::: "memory");
            const unsigned short* vg = VFb + (size_t)(kt + 1) * 8192;
            #pragma unroll
            for (int j = 0; j < 16; ++j) glds16(vg + j * 512 + lane8, Vl + j * 512);
        }
    }

    lsum += __shfl_xor(lsum, 16);
    lsum += __shfl_xor(lsum, 32);
    __syncthreads();
    float* Obuf = (float*)arena;
    float* Lbuf = (float*)(arena + 16 * 260 * 4);
    if (wave == 0) {
        if (lane < 16) Lbuf[lane] = lsum;
        #pragma unroll
        for (int j = 0; j < 16; ++j)
            #pragma unroll
            for (int g = 0; g < 4; ++g)
                Obuf[(q * 4 + g) * 260 + j * 16 + r] = o[j][g];
    }
    __syncthreads();
    if (wave == 1) {
        if (lane < 16) Lbuf[lane] += lsum;
        #pragma unroll
        for (int j = 0; j < 16; ++j)
            #pragma unroll
            for (int g = 0; g < 4; ++g)
                Obuf[(q * 4 + g) * 260 + j * 16 + r] += o[j][g];
    }
    __syncthreads();

    float linv[4];
    #pragma unroll
    for (int g = 0; g < 4; ++g) linv[g] = 1.0f / Lbuf[q * 4 + g];
    unsigned short* AOt = AOF + (size_t)(batch * 256 + qt) * 8 * 512;
    #pragma unroll
    for (int jj = 0; jj < 8; ++jj) {
        int j = wave * 8 + jj;
        int d = j * 16 + r;
        int ks = d >> 5, qp = (d >> 3) & 3, e = d & 7;
        #pragma unroll
        for (int g = 0; g < 4; ++g)
            AOt[ks * 512 + (qp * 16 + q * 4 + g) * 8 + e] =
                f2bf(Obuf[(q * 4 + g) * 260 + j * 16 + r] * linv[g]);
    }
}

// ---------- kernel 4: WO GEMM + residual + RMSNorm2, glds-staged ----------
__global__ __launch_bounds__(256) void k_wo(
    const unsigned short* __restrict__ AOF, const unsigned short* __restrict__ woF,
    const float* __restrict__ bo, const float* __restrict__ x,
    const float* __restrict__ mnw, float* __restrict__ x2,
    unsigned short* __restrict__ hnF)
{
    __shared__ __align__(16) unsigned short sb[2][20 * 512];
    int bid = blockIdx.x;
    int wave = threadIdx.x >> 6, lane = threadIdx.x & 63;
    int m0 = bid * 64 + wave * 16;
    int mt = bid * 4 + wave;
    int mtB = bid * 4;
    int q = lane >> 4, r = lane & 15;
    int lane8 = lane * 8;

    #define WO_STAGE(ks, buf)                                                    \
        { int _k = (ks);                                                         \
          _Pragma("unroll")                                                      \
          for (int t = 0; t < 5; ++t) {                                          \
              int f = wave * 5 + t;                                              \
              const unsigned short* g = (f < 4)                                  \
                  ? AOF + ((mtB + f) * 8 + _k) * 512                             \
                  : woF + ((f - 4) * 8 + _k) * 512;                              \
              glds16(g + lane8, &sb[buf][f * 512]);                              \
          } }

    f32x4 acc[16] = {};
    WO_STAGE(0, 0)
    for (int ks = 0; ks < 8; ++ks) {
        int cur = ks & 1;
        if (ks + 1 < 8) { WO_STAGE(ks + 1, cur ^ 1) }
        if (ks + 1 < 8) asm volatile("s_waitcnt vmcnt(5)" ::: "memory");
        else            asm volatile("s_waitcnt vmcnt(0)" ::: "memory");
        asm volatile("s_barrier" ::: "memory");
        bfrag a = *(const bfrag*)(&sb[cur][wave * 512] + lane8);
        #pragma unroll
        for (int j = 0; j < 16; ++j) {
            bfrag b = *(const bfrag*)(&sb[cur][(4 + j) * 512] + lane8);
            acc[j] = mfma16(a, b, acc[j]);
        }
        asm volatile("s_barrier" ::: "memory");
    }
    #undef WO_STAGE

    float ss[4] = {0.f, 0.f, 0.f, 0.f};
    #pragma unroll
    for (int j = 0; j < 16; ++j) {
        int n = j * 16 + r;
        float bz = bo[n];
        #pragma unroll
        for (int g = 0; g < 4; ++g) {
            int row = m0 + q * 4 + g;
            float v = acc[j][g] + bz + x[row * DIM + n];
            acc[j][g] = v;
            ss[g] += v * v;
            x2[row * DIM + n] = v;
        }
    }
    #pragma unroll
    for (int g = 0; g < 4; ++g) {
        #pragma unroll
        for (int off = 1; off < 16; off <<= 1) ss[g] += __shfl_xor(ss[g], off);
    }
    #pragma unroll
    for (int j = 0; j < 16; ++j) {
        int n = j * 16 + r;
        int ks = n >> 5, qp = (n >> 3) & 3, e = n & 7;
        float wn = mnw[n];
        #pragma unroll
        for (int g = 0; g < 4; ++g) {
            float inv = rsqrtf(ss[g] * (1.0f / DIM) + 1e-6f);
            hnF[(mt * 8 + ks) * 512 + (qp * 16 + q * 4 + g) * 8 + e]
                = f2bf(acc[j][g] * inv * wn);
        }
    }
}

// ---------- kernel 5: W1 GEMM + GELU, glds-staged (M=16384,N=1024,K=256) ----------
__global__ __launch_bounds__(256) void k_w1(
    const unsigned short* __restrict__ hnF, const unsigned short* __restrict__ w1F,
    const float* __restrict__ b1, unsigned short* __restrict__ hF)
{
    __shared__ __align__(16) unsigned short sb[2][20 * 512];
    int bid = blockIdx.x;
    int wave = threadIdx.x >> 6, lane = threadIdx.x & 63;
    int m0 = (bid >> 2) * 64;
    int n0 = (bid & 3) * 256 + wave * 64;
    int mt = m0 >> 4, ntb = (bid & 3) * 16;
    int q = lane >> 4, r = lane & 15;
    int lane8 = lane * 8;

    #define W1_STAGE(ks, buf)                                                    \
        { int _k = (ks);                                                         \
          _Pragma("unroll")                                                      \
          for (int t = 0; t < 5; ++t) {                                          \
              int f = wave * 5 + t;                                              \
              const unsigned short* g = (f < 4)                                  \
                  ? hnF + ((mt + f) * 8 + _k) * 512                              \
                  : w1F + ((ntb + f - 4) * 8 + _k) * 512;                        \
              glds16(g + lane8, &sb[buf][f * 512]);                              \
          } }

    f32x4 acc[4][4] = {};
    W1_STAGE(0, 0)
    for (int ks = 0; ks < 8; ++ks) {
        int cur = ks & 1;
        if (ks + 1 < 8) { W1_STAGE(ks + 1, cur ^ 1) }
        if (ks + 1 < 8) asm volatile("s_waitcnt vmcnt(5)" ::: "memory");
        else            asm volatile("s_waitcnt vmcnt(0)" ::: "memory");
        asm volatile("s_barrier" ::: "memory");
        bfrag a[4], b[4];
        #pragma unroll
        for (int i = 0; i < 4; ++i) a[i] = *(const bfrag*)(&sb[cur][i * 512] + lane8);
        #pragma unroll
        for (int j = 0; j < 4; ++j) b[j] = *(const bfrag*)(&sb[cur][(4 + wave * 4 + j) * 512] + lane8);
        #pragma unroll
        for (int i = 0; i < 4; ++i)
            #pragma unroll
            for (int j = 0; j < 4; ++j) acc[i][j] = mfma16(a[i], b[j], acc[i][j]);
        asm volatile("s_barrier" ::: "memory");
    }
    #undef W1_STAGE

    #pragma unroll
    for (int j = 0; j < 4; ++j) {
        int n = n0 + j * 16 + r;
        int ks = n >> 5, qp = (n >> 3) & 3, e = n & 7;
        float bz = b1[n];
        #pragma unroll
        for (int i = 0; i < 4; ++i)
            #pragma unroll
            for (int g = 0; g < 4; ++g) {
                float v = acc[i][j][g] + bz;
                float ge = 0.5f * v * (1.0f + erff(v * 0.70710678118654752f));
                hF[((mt + i) * 32 + ks) * 512 + (qp * 16 + q * 4 + g) * 8 + e] = f2bf(ge);
            }
    }
}

// ---------- kernel 6: W2 GEMM + residual, glds-staged (M=16384,N=256,K=1024) ----------
__global__ __launch_bounds__(256) void k_w2(
    const unsigned short* __restrict__ hF, const unsigned short* __restrict__ w2F,
    const float* __restrict__ b2, const float* __restrict__ x2,
    float* __restrict__ out)
{
    __shared__ __align__(16) unsigned short sb[2][20 * 512];
    int bid = blockIdx.x;
    int wave = threadIdx.x >> 6, lane = threadIdx.x & 63;
    int m0 = bid * 64;
    int n0 = wave * 64;
    int mt = m0 >> 4;
    int q = lane >> 4, r = lane & 15;
    int lane8 = lane * 8;

    #define W2_STAGE(ks, buf)                                                    \
        { int _k = (ks);                                                         \
          _Pragma("unroll")                                                      \
          for (int t = 0; t < 5; ++t) {                                          \
              int f = wave * 5 + t;                                              \
              const unsigned short* g = (f < 4)                                  \
                  ? hF  + ((mt + f) * 32 + _k) * 512                             \
                  : w2F + ((f - 4) * 32 + _k) * 512;                             \
              glds16(g + lane8, &sb[buf][f * 512]);                              \
          } }

    f32x4 acc[4][4] = {};
    W2_STAGE(0, 0)
    for (int ks = 0; ks < 32; ++ks) {
        int cur = ks & 1;
        if (ks + 1 < 32) { W2_STAGE(ks + 1, cur ^ 1) }
        if (ks + 1 < 32) asm volatile("s_waitcnt vmcnt(5)" ::: "memory");
        else             asm volatile("s_waitcnt vmcnt(0)" ::: "memory");
        asm volatile("s_barrier" ::: "memory");
        bfrag a[4], b[4];
        #pragma unroll
        for (int i = 0; i < 4; ++i) a[i] = *(const bfrag*)(&sb[cur][i * 512] + lane8);
        #pragma unroll
        for (int j = 0; j < 4; ++j) b[j] = *(const bfrag*)(&sb[cur][(4 + wave * 4 + j) * 512] + lane8);
        #pragma unroll
        for (int i = 0; i < 4; ++i)
            #pragma unroll
            for (int j = 0; j < 4; ++j) acc[i][j] = mfma16(a[i], b[j], acc[i][j]);
        asm volatile("s_barrier" ::: "memory");
    }
    #undef W2_STAGE

    #pragma unroll
    for (int j = 0; j < 4; ++j) {
        int n = n0 + j * 16 + r;
        float bz = b2[n];
        #pragma unroll
        for (int i = 0; i < 4; ++i)
            #pragma unroll
            for (int g = 0; g < 4; ++g) {
                int row = m0 + i * 16 + q * 4 + g;
                out[row * DIM + n] = acc[i][j][g] + bz + x2[row * DIM + n];
            }
    }
}

// ---------- workspace layout (bytes) ----------
#define OFF_WQB 0u
#define OFF_WKB 131072u
#define OFF_WVB 262144u
#define OFF_WOB 393216u
#define OFF_W1B 524288u
#define OFF_W2B 1048576u
#define OFF_XN  1572864u
#define OFF_Q   9961472u
#define OFF_KF  18350080u
#define OFF_VF  26738688u
#define OFF_AO  35127296u
#define OFF_X2  43515904u
#define OFF_HN  60293120u
#define OFF_H   OFF_XN      /* hF (32MB) aliases xnF/Q/KF/VF — all dead by then */

extern "C" void kernel_launch(void* const* d_in, const int* in_sizes, int n_in,
                              void* d_out, int out_size, void* d_ws, size_t ws_size,
                              hipStream_t stream) {
    const float* x   = (const float*)d_in[0];
    const float* anw = (const float*)d_in[1];
    const float* mnw = (const float*)d_in[2];
    const float* wq  = (const float*)d_in[3];
    const float* bq  = (const float*)d_in[4];
    const float* wk  = (const float*)d_in[5];
    const float* bk  = (const float*)d_in[6];
    const float* wv  = (const float*)d_in[7];
    const float* bv  = (const float*)d_in[8];
    const float* wo  = (const float*)d_in[9];
    const float* bo  = (const float*)d_in[10];
    const float* w1  = (const float*)d_in[11];
    const float* b1  = (const float*)d_in[12];
    const float* w2  = (const float*)d_in[13];
    const float* b2  = (const float*)d_in[14];
    float* out = (float*)d_out;

    char* ws = (char*)d_ws;
    unsigned short* wqF = (unsigned short*)(ws + OFF_WQB);
    unsigned short* wkF = (unsigned short*)(ws + OFF_WKB);
    unsigned short* wvF = (unsigned short*)(ws + OFF_WVB);
    unsigned short* woF = (unsigned short*)(ws + OFF_WOB);
    unsigned short* w1F = (unsigned short*)(ws + OFF_W1B);
    unsigned short* w2F = (unsigned short*)(ws + OFF_W2B);
    unsigned short* xnF = (unsigned short*)(ws + OFF_XN);
    unsigned short* Qp  = (unsigned short*)(ws + OFF_Q);
    unsigned short* KFp = (unsigned short*)(ws + OFF_KF);
    unsigned short* VFp = (unsigned short*)(ws + OFF_VF);
    unsigned short* AOF = (unsigned short*)(ws + OFF_AO);
    float*          x2  = (float*)         (ws + OFF_X2);
    unsigned short* hnF = (unsigned short*)(ws + OFF_HN);
    unsigned short* hFp = (unsigned short*)(ws + OFF_H);

    k_prep<<<dim3(4480), dim3(256), 0, stream>>>(x, anw, wq, wk, wv, wo, w1, w2,
                                                 wqF, wkF, wvF, woF, w1F, w2F, xnF);
    k_qkv <<<dim3(768),  dim3(256), 0, stream>>>(xnF, wqF, wkF, wvF, bq, bk, bv, Qp, KFp, VFp);
    k_attn<<<dim3(1024), dim3(128), 0, stream>>>(Qp, KFp, VFp, AOF);
    k_wo  <<<dim3(256),  dim3(256), 0, stream>>>(AOF, woF, bo, x, mnw, x2, hnF);
    k_w1  <<<dim3(1024), dim3(256), 0, stream>>>(hnF, w1F, b1, hFp);
    k_w2  <<<dim3(256),  dim3(256), 0, stream>>>(hFp, w2F, b2, x2, out);
}